// Round 11
// baseline (442.225 us; speedup 1.0000x reference)
//
#include <hip/hip_runtime.h>
#include <hip/hip_bf16.h>

typedef float f32x4 __attribute__((ext_vector_type(4)));
typedef short s16x8 __attribute__((ext_vector_type(8)));
typedef short s16x4 __attribute__((ext_vector_type(4)));
typedef __bf16 bf16x8 __attribute__((ext_vector_type(8)));
typedef unsigned short u16;

#define DEVI __device__ __forceinline__

static constexpr int    HW      = 16384;
static constexpr size_t BSTRIDE = (size_t)256 * HW;

// ---- workspace byte offsets ----
static constexpr size_t oXBT   = 0;                                    // bf16 [8][HW][256]
static constexpr size_t oEK    = oXBT  + (size_t)8 * HW * 256 * 2;     // bf16 [8][256][HW] exp(keys)
static constexpr size_t oQT    = oEK   + (size_t)8 * 256 * HW * 2;     // bf16 [8][HW][256] softmaxed Q, transposed
static constexpr size_t oVB    = oQT   + (size_t)8 * HW * 256 * 2;     // bf16 [8][256][HW]
static constexpr size_t oWK    = oVB   + (size_t)8 * 256 * HW * 2;     // bf16 [768][256]
static constexpr size_t oBIAS  = oWK   + (size_t)768 * 256 * 2;        // f32 [768]
static constexpr size_t oISE   = oBIAS + 4096;                         // f32 [8][256] inv row-sum-exp
static constexpr size_t oPS    = oISE  + 8192;                         // f32 [256][8][256] rowsum partials
static constexpr size_t oCTX   = oPS   + (size_t)256 * 2048 * 4;       // f32 [64][32][32]
static constexpr size_t oMB    = oCTX  + (size_t)64 * 1024 * 4;        // bf16 [8][256][256]
static constexpr size_t oCPART = oMB   + (size_t)8 * 256 * 256 * 2;    // f32 [4096][1024]
static constexpr size_t oMPART = oCPART + (size_t)4096 * 1024 * 4;     // f32 [8][8][HW]

DEVI float bf2f(short x) {
  unsigned u = ((unsigned)(unsigned short)x) << 16;
  return __builtin_bit_cast(float, u);
}
DEVI u16 f2bf(float x) { return __builtin_bit_cast(u16, (__bf16)x); }

// ---------------- prep: pack Wk|Wq|Wv -> bf16 [768][256], biases -> f32 [768] ----------------
__global__ __launch_bounds__(256) void k_prep(
    const float* __restrict__ Wk, const float* __restrict__ Wq, const float* __restrict__ Wv,
    const float* __restrict__ bk, const float* __restrict__ bq, const float* __restrict__ bv,
    u16* __restrict__ Wkqv, float* __restrict__ bias)
{
  int i = blockIdx.x * 256 + threadIdx.x;
  for (int p = i; p < 768 * 256; p += 64 * 256) {
    float v = (p < 65536) ? Wk[p] : (p < 131072 ? Wq[p - 65536] : Wv[p - 131072]);
    Wkqv[p] = f2bf(v);
  }
  if (i < 768) bias[i] = (i < 256) ? bk[i] : (i < 512 ? bq[i - 256] : bv[i - 512]);
}

// ---------------- transpose x [8][256][HW] f32 -> bf16 [8][HW][256] ----------------
__global__ __launch_bounds__(256) void k_transpose(const float* __restrict__ in_, u16* __restrict__ out)
{
  __shared__ u16 lds[64 * 256];
  const int t = threadIdx.x;
  const int n = blockIdx.y;
  const int s0 = blockIdx.x * 64;
  const float* src = in_ + ((size_t)n * 256 + t) * HW + s0;
  #pragma unroll
  for (int i = 0; i < 16; ++i) {
    f32x4 v = *(const f32x4*)(src + i * 4);
    #pragma unroll
    for (int j = 0; j < 4; ++j) lds[(i * 4 + j) * 256 + t] = f2bf(v[j]);
  }
  __syncthreads();
  s16x8* gp = (s16x8*)(out + (size_t)n * BSTRIDE + (size_t)s0 * 256);
  const s16x8* lp = (const s16x8*)lds;
  #pragma unroll
  for (int i = 0; i < 8; ++i) gp[t + i * 256] = lp[t + i * 256];
}

// ======== no-LDS direct-load GEMM cores (ctx_part pattern scaled up) ========
// 128x128 tile, BK=32, fragments loaded straight from global (L2/L3-hot), zero barriers.
// Swapped acc[sf][mf][r]: s = s0+wn+sf*16+l4*4+r ; m = m0+wm+mf*16+l15.

// ---------------- keys+values projection ----------------
__global__ __launch_bounds__(256, 3) void k_projKV(
    const u16* __restrict__ W, const u16* __restrict__ xbT, const float* __restrict__ bias,
    u16* __restrict__ ek, u16* __restrict__ vb, float* __restrict__ ps)
{
  const int t = threadIdx.x;
  const int L = blockIdx.x;
  const int n = L & 7;                 // batch == XCD
  const int idx = L >> 3;              // 0..511
  const int mbi = idx & 3;             // mb-adjacent -> B-panel L2 reuse
  const int sb  = idx >> 2;            // 0..127
  const bool isK = (mbi < 2);
  const int m0 = (mbi & 1) * 128;
  const int aBase = (isK ? 0 : 512) + m0;
  const int s0 = sb * 128;
  const int lane = t & 63;
  const int l15 = lane & 15, l4 = (lane >> 4) & 3;
  const int wv = t >> 6;
  const int wm = (wv & 1) * 64, wn = (wv >> 1) * 64;

  const u16* Ab = W + (size_t)aBase * 256;
  const u16* Bb = xbT + (size_t)n * BSTRIDE + (size_t)s0 * 256;

  float biasv[4];
  #pragma unroll
  for (int mf = 0; mf < 4; ++mf) biasv[mf] = bias[aBase + wm + mf * 16 + l15];

  f32x4 acc[4][4] = {};                // [sf][mf]
  #pragma unroll
  for (int kt = 0; kt < 8; ++kt) {
    const int k0 = kt * 32 + l4 * 8;
    bf16x8 af[4], bf[4];
    #pragma unroll
    for (int g = 0; g < 4; ++g) {
      af[g] = *(const bf16x8*)(Ab + (size_t)(wm + g * 16 + l15) * 256 + k0);
      bf[g] = *(const bf16x8*)(Bb + (size_t)(wn + g * 16 + l15) * 256 + k0);
    }
    #pragma unroll
    for (int sf = 0; sf < 4; ++sf)
      #pragma unroll
      for (int mf = 0; mf < 4; ++mf)
        acc[sf][mf] = __builtin_amdgcn_mfma_f32_16x16x32_bf16(bf[sf], af[mf], acc[sf][mf], 0, 0, 0);
  }

  u16* outb = (isK ? ek : vb) + (size_t)n * BSTRIDE;
  if (isK) {
    float rs[4] = {0.f, 0.f, 0.f, 0.f};
    #pragma unroll
    for (int sf = 0; sf < 4; ++sf)
      #pragma unroll
      for (int mf = 0; mf < 4; ++mf) {
        s16x4 pk;
        #pragma unroll
        for (int r = 0; r < 4; ++r) {
          const float e = __expf(acc[sf][mf][r] + biasv[mf]);
          rs[mf] += e;
          pk[r] = (short)f2bf(e);
        }
        *(s16x4*)(outb + (size_t)(m0 + wm + mf * 16 + l15) * HW + s0 + wn + sf * 16 + l4 * 4) = pk;
      }
    #pragma unroll
    for (int mf = 0; mf < 4; ++mf) {
      float v = rs[mf];
      v += __shfl_xor(v, 16); v += __shfl_xor(v, 32);
      if (l4 == 0)
        ps[((size_t)(sb * 2 + (wn >> 6))) * 2048 + n * 256 + m0 + wm + mf * 16 + l15] = v;
    }
  } else {
    #pragma unroll
    for (int sf = 0; sf < 4; ++sf)
      #pragma unroll
      for (int mf = 0; mf < 4; ++mf) {
        s16x4 pk;
        #pragma unroll
        for (int r = 0; r < 4; ++r) pk[r] = (short)f2bf(acc[sf][mf][r] + biasv[mf]);
        *(s16x4*)(outb + (size_t)(m0 + wm + mf * 16 + l15) * HW + s0 + wn + sf * 16 + l4 * 4) = pk;
      }
  }
}

// ---------------- queries projection: no-LDS core (unswapped) + r7 softmax/transpose epilogue ----------------
__global__ __launch_bounds__(256, 3) void k_projQ(
    const u16* __restrict__ W, const u16* __restrict__ xbT, const float* __restrict__ bias,
    u16* __restrict__ qT)
{
  __shared__ u16 smem[17408];          // epilogue transpose overlay only (128 x 136)
  const int t = threadIdx.x;
  const int L = blockIdx.x;
  const int n  = L & 7;
  const int idx = L >> 3;              // 0..255
  const int mbq = idx & 1;
  const int sb  = idx >> 1;            // 0..127
  const int m0 = 256 + mbq * 128, s0 = sb * 128;
  const int lane = t & 63;
  const int l15 = lane & 15, l4 = (lane >> 4) & 3;
  const int wv = t >> 6;
  const int wm = (wv & 1) * 64, wn = (wv >> 1) * 64;

  const u16* Ab = W + (size_t)m0 * 256;
  const u16* Bb = xbT + (size_t)n * BSTRIDE + (size_t)s0 * 256;

  f32x4 acc[4][4] = {};                // [mg][ng] unswapped: m = wm+mg*16+l4*4+r ; s = wn+ng*16+l15
  #pragma unroll
  for (int kt = 0; kt < 8; ++kt) {
    const int k0 = kt * 32 + l4 * 8;
    bf16x8 af[4], bf[4];
    #pragma unroll
    for (int g = 0; g < 4; ++g) {
      af[g] = *(const bf16x8*)(Ab + (size_t)(wm + g * 16 + l15) * 256 + k0);
      bf[g] = *(const bf16x8*)(Bb + (size_t)(wn + g * 16 + l15) * 256 + k0);
    }
    #pragma unroll
    for (int mg = 0; mg < 4; ++mg)
      #pragma unroll
      for (int ng = 0; ng < 4; ++ng)
        acc[mg][ng] = __builtin_amdgcn_mfma_f32_16x16x32_bf16(af[mg], bf[ng], acc[mg][ng], 0, 0, 0);
  }

  #pragma unroll
  for (int mg = 0; mg < 4; ++mg)
    #pragma unroll
    for (int r = 0; r < 4; ++r) {
      const float bb = bias[m0 + wm + mg * 16 + l4 * 4 + r];
      #pragma unroll
      for (int ng = 0; ng < 4; ++ng) acc[mg][ng][r] += bb;
    }

  #pragma unroll
  for (int hh = 0; hh < 2; ++hh)
    #pragma unroll
    for (int ng = 0; ng < 4; ++ng) {
      float s = 0.f;
      #pragma unroll
      for (int mg = hh * 2; mg < hh * 2 + 2; ++mg)
        #pragma unroll
        for (int r = 0; r < 4; ++r) { const float e = __expf(acc[mg][ng][r]); acc[mg][ng][r] = e; s += e; }
      s += __shfl_xor(s, 16);
      s += __shfl_xor(s, 32);
      const float inv = 1.f / s;
      #pragma unroll
      for (int mg = hh * 2; mg < hh * 2 + 2; ++mg)
        #pragma unroll
        for (int r = 0; r < 4; ++r) acc[mg][ng][r] *= inv;
    }
  __syncthreads();
  #pragma unroll
  for (int mg = 0; mg < 4; ++mg)
    #pragma unroll
    for (int ng = 0; ng < 4; ++ng)
      #pragma unroll
      for (int r = 0; r < 4; ++r) {
        const int srow = wn + ng * 16 + l15;
        const int mcol = wm + mg * 16 + l4 * 4 + r;
        smem[srow * 136 + mcol] = f2bf(acc[mg][ng][r]);
      }
  __syncthreads();
  u16* O = qT + (size_t)n * BSTRIDE + (size_t)s0 * 256 + mbq * 128;
  #pragma unroll
  for (int it = 0; it < 8; ++it) {
    const int row = it * 16 + (t >> 4);
    *(s16x8*)(O + (size_t)row * 256 + (t & 15) * 8) = *(const s16x8*)&smem[row * 136 + (t & 15) * 8];
  }
}

// ---------------- final GEMM: attn[o][s] = sum_m M[o][m] Q[s][m] + br, f32, no-LDS ----------------
__global__ __launch_bounds__(256, 3) void k_attn2(
    const u16* __restrict__ Mb, const u16* __restrict__ qT, const float* __restrict__ br,
    float* __restrict__ Out)
{
  const int t = threadIdx.x;
  const int L = blockIdx.x;
  const int n = L & 7;
  const int idx = L >> 3;              // 0..255
  const int mb = idx & 1;
  const int sb = idx >> 1;             // 0..127
  const int m0 = mb * 128;
  const int s0 = sb * 128;
  const int lane = t & 63;
  const int l15 = lane & 15, l4 = (lane >> 4) & 3;
  const int wv = t >> 6;
  const int wm = (wv & 1) * 64, wn = (wv >> 1) * 64;

  const u16* Ab = Mb + (size_t)n * 65536 + (size_t)m0 * 256;
  const u16* Bb = qT + (size_t)n * BSTRIDE + (size_t)s0 * 256;

  float biasv[4];
  #pragma unroll
  for (int mf = 0; mf < 4; ++mf) biasv[mf] = br[m0 + wm + mf * 16 + l15];

  f32x4 acc[4][4] = {};                // [sf][mf] swapped
  #pragma unroll
  for (int kt = 0; kt < 8; ++kt) {
    const int k0 = kt * 32 + l4 * 8;
    bf16x8 af[4], bf[4];
    #pragma unroll
    for (int g = 0; g < 4; ++g) {
      af[g] = *(const bf16x8*)(Ab + (size_t)(wm + g * 16 + l15) * 256 + k0);
      bf[g] = *(const bf16x8*)(Bb + (size_t)(wn + g * 16 + l15) * 256 + k0);
    }
    #pragma unroll
    for (int sf = 0; sf < 4; ++sf)
      #pragma unroll
      for (int mf = 0; mf < 4; ++mf)
        acc[sf][mf] = __builtin_amdgcn_mfma_f32_16x16x32_bf16(bf[sf], af[mf], acc[sf][mf], 0, 0, 0);
  }

  float* ob = Out + (size_t)n * BSTRIDE;
  #pragma unroll
  for (int sf = 0; sf < 4; ++sf)
    #pragma unroll
    for (int mf = 0; mf < 4; ++mf) {
      f32x4 o = acc[sf][mf] + biasv[mf];
      *(f32x4*)(ob + (size_t)(m0 + wm + mf * 16 + l15) * HW + s0 + wn + sf * 16 + l4 * 4) = o;
    }
}

// ---------------- reduce rowsum partials -> inverse ----------------
__global__ __launch_bounds__(256) void k_inv(const float* __restrict__ ps, float* __restrict__ ise)
{
  const int i = blockIdx.x * 256 + threadIdx.x;   // 2048
  float s = 0.f;
  for (int b = 0; b < 256; ++b) s += ps[(size_t)b * 2048 + i];
  ise[i] = 1.f / s;
}

// ---------------- ctx split-K partials + fused attention-map partials ----------------
__global__ __launch_bounds__(64) void k_ctx_part(
    const u16* __restrict__ ek, const u16* __restrict__ vb, const float* __restrict__ ise,
    float* __restrict__ cpart, float* __restrict__ mpart)
{
  const int blk = blockIdx.x;            // nh*64 + chunk
  const int chunk = blk & 63, nh = blk >> 6;
  const int h = nh & 7, n = nh >> 3;
  const int lane = threadIdx.x;
  const int l15 = lane & 15, l4 = lane >> 4;
  const u16* kb = ek + ((size_t)n * 256 + h * 32) * HW;
  const u16* vv = vb + ((size_t)n * 256 + h * 32) * HW;
  const float iv0 = ise[n * 256 + h * 32 + l15];
  const float iv1 = ise[n * 256 + h * 32 + 16 + l15];
  f32x4 acc[2][2] = {};
  float macc[8][8] = {};
  const int sbase = chunk * 256 + l4 * 8;
  #pragma unroll
  for (int ks = 0; ks < 8; ++ks) {
    const int sb = sbase + ks * 32;
    bf16x8 ef[2], vf[2];
    #pragma unroll
    for (int g = 0; g < 2; ++g) {
      ef[g] = *(const bf16x8*)(kb + (size_t)(g * 16 + l15) * HW + sb);
      vf[g] = *(const bf16x8*)(vv + (size_t)(g * 16 + l15) * HW + sb);
    }
    #pragma unroll
    for (int j = 0; j < 8; ++j)
      macc[ks][j] = fmaf(iv0, (float)ef[0][j], fmaf(iv1, (float)ef[1][j], macc[ks][j]));
    #pragma unroll
    for (int a = 0; a < 2; ++a)
      #pragma unroll
      for (int b = 0; b < 2; ++b)
        acc[a][b] = __builtin_amdgcn_mfma_f32_16x16x32_bf16(ef[a], vf[b], acc[a][b], 0, 0, 0);
  }
  float* op = cpart + (size_t)blk * 1024;
  #pragma unroll
  for (int a = 0; a < 2; ++a)
    #pragma unroll
    for (int b = 0; b < 2; ++b)
      #pragma unroll
      for (int r = 0; r < 4; ++r)
        op[(a * 16 + l4 * 4 + r) * 32 + b * 16 + l15] = acc[a][b][r];
  #pragma unroll
  for (int ks = 0; ks < 8; ++ks)
    #pragma unroll
    for (int j = 0; j < 8; ++j) {
      float v = macc[ks][j];
      v += __shfl_xor(v, 1); v += __shfl_xor(v, 2);
      v += __shfl_xor(v, 4); v += __shfl_xor(v, 8);
      macc[ks][j] = v;
    }
  if (l15 == 0) {
    float* mp = mpart + ((size_t)h * 8 + n) * HW + sbase;
    #pragma unroll
    for (int ks = 0; ks < 8; ++ks) {
      f32x4 a = {macc[ks][0], macc[ks][1], macc[ks][2], macc[ks][3]};
      f32x4 b = {macc[ks][4], macc[ks][5], macc[ks][6], macc[ks][7]};
      *(f32x4*)(mp + ks * 32)     = a;
      *(f32x4*)(mp + ks * 32 + 4) = b;
    }
  }
}

// ---------------- reduce ctx partials, normalize; emit context_last (h==7) ----------------
__global__ __launch_bounds__(256) void k_ctx_reduce(
    const float* __restrict__ cpart, const float* __restrict__ ise,
    float* __restrict__ ctx, float* __restrict__ dctx)
{
  const int nh = blockIdx.x, n = nh >> 3, h = nh & 7, t = threadIdx.x;
  f32x4 a = {};
  for (int c = 0; c < 64; ++c) a += *(const f32x4*)(cpart + ((size_t)nh * 64 + c) * 1024 + t * 4);
  const float inv = ise[n * 256 + h * 32 + (t >> 3)];
  a *= inv;
  *(f32x4*)(ctx + (size_t)nh * 1024 + t * 4) = a;
  if (h == 7) *(f32x4*)(dctx + (size_t)n * 1024 + t * 4) = a;
}

// ---------------- M[n][o][h*32+k] = sum_v Wr[o][h*32+v] * ctx[n][h][k][v] ----------------
__global__ __launch_bounds__(256) void k_mmat(
    const float* __restrict__ ctx, const float* __restrict__ Wr, u16* __restrict__ Mb)
{
  const int nh = blockIdx.x, n = nh >> 3, h = nh & 7, o = threadIdx.x;
  __shared__ float cl[1024];
  #pragma unroll
  for (int i = 0; i < 4; ++i) cl[o + i * 256] = ctx[(size_t)nh * 1024 + o + i * 256];
  __syncthreads();
  float wr[32];
  const float* wp = Wr + (size_t)o * 256 + h * 32;
  #pragma unroll
  for (int v = 0; v < 32; ++v) wr[v] = wp[v];
  u16* mp = Mb + ((size_t)n * 256 + o) * 256 + h * 32;
  #pragma unroll 4
  for (int k = 0; k < 32; ++k) {
    float s = 0.f;
    #pragma unroll
    for (int v = 0; v < 32; ++v) s += wr[v] * cl[k * 32 + v];
    mp[k] = f2bf(s);
  }
}

// ---------------- attention_map: sum 8 head partials, /256 ----------------
__global__ __launch_bounds__(256) void k_map_reduce(const float* __restrict__ mpart, float* __restrict__ dmap)
{
  const int i = blockIdx.x * 256 + threadIdx.x;   // 32768 threads, f32x4 each
  f32x4 a = {};
  #pragma unroll
  for (int h = 0; h < 8; ++h) a += *(const f32x4*)(mpart + (size_t)h * 131072 + (size_t)i * 4);
  a *= (1.0f / 256.0f);
  *(f32x4*)(dmap + (size_t)i * 4) = a;
}

extern "C" void kernel_launch(void* const* d_in, const int* in_sizes, int n_in,
                              void* d_out, int out_size, void* d_ws, size_t ws_size,
                              hipStream_t stream)
{
  (void)in_sizes; (void)n_in; (void)out_size; (void)ws_size;
  const float* x  = (const float*)d_in[0];
  const float* Wk = (const float*)d_in[1];
  const float* bk = (const float*)d_in[2];
  const float* Wq = (const float*)d_in[3];
  const float* bq = (const float*)d_in[4];
  const float* Wv = (const float*)d_in[5];
  const float* bv = (const float*)d_in[6];
  const float* Wr = (const float*)d_in[7];
  const float* br = (const float*)d_in[8];

  char* ws = (char*)d_ws;
  u16*   xbT  = (u16*)(ws + oXBT);
  u16*   ek   = (u16*)(ws + oEK);
  u16*   qT   = (u16*)(ws + oQT);
  u16*   vb   = (u16*)(ws + oVB);
  u16*   Wkqv = (u16*)(ws + oWK);
  float* bias = (float*)(ws + oBIAS);
  float* ise  = (float*)(ws + oISE);
  float* ps   = (float*)(ws + oPS);
  float* ctx  = (float*)(ws + oCTX);
  u16*   Mb   = (u16*)(ws + oMB);
  float* cpart= (float*)(ws + oCPART);
  float* mpart= (float*)(ws + oMPART);

  float* attn = (float*)d_out;                    // [8][256][HW]
  float* dctx = (float*)d_out + 33554432;         // [8][32][32]
  float* dmap = (float*)d_out + 33562624;         // [8][HW]

  k_prep<<<64, 256, 0, stream>>>(Wk, Wq, Wv, bk, bq, bv, Wkqv, bias);
  k_transpose<<<dim3(256, 8), 256, 0, stream>>>(x, xbT);
  k_projKV<<<4096, 256, 0, stream>>>(Wkqv, xbT, bias, ek, vb, ps);
  k_inv<<<8, 256, 0, stream>>>(ps, ise);
  k_projQ<<<2048, 256, 0, stream>>>(Wkqv, xbT, bias, qT);
  k_ctx_part<<<4096, 64, 0, stream>>>(ek, vb, ise, cpart, mpart);
  k_ctx_reduce<<<64, 256, 0, stream>>>(cpart, ise, ctx, dctx);
  k_mmat<<<64, 256, 0, stream>>>(ctx, Wr, Mb);
  k_map_reduce<<<128, 256, 0, stream>>>(mpart, dmap);
  k_attn2<<<2048, 256, 0, stream>>>(Mb, qT, br, attn);
}

// Round 12
// 283.804 us; speedup vs baseline: 1.5582x; 1.5582x over previous
//
#include <hip/hip_runtime.h>
#include <hip/hip_bf16.h>

typedef float f32x4 __attribute__((ext_vector_type(4)));
typedef short s16x8 __attribute__((ext_vector_type(8)));
typedef short s16x4 __attribute__((ext_vector_type(4)));
typedef __bf16 bf16x8 __attribute__((ext_vector_type(8)));
typedef unsigned short u16;

#define DEVI __device__ __forceinline__

static constexpr int    HW      = 16384;
static constexpr size_t BSTRIDE = (size_t)256 * HW;

// ---- workspace byte offsets ----
static constexpr size_t oXBT   = 0;                                    // bf16 [8][HW][256]
static constexpr size_t oEK    = oXBT  + (size_t)8 * HW * 256 * 2;     // bf16 [8][256][HW] exp(keys)
static constexpr size_t oQT    = oEK   + (size_t)8 * 256 * HW * 2;     // bf16 [8][HW][256] softmaxed Q, transposed
static constexpr size_t oVB    = oQT   + (size_t)8 * HW * 256 * 2;     // bf16 [8][256][HW]
static constexpr size_t oWK    = oVB   + (size_t)8 * 256 * HW * 2;     // bf16 [768][256]
static constexpr size_t oBIAS  = oWK   + (size_t)768 * 256 * 2;        // f32 [768]
static constexpr size_t oISE   = oBIAS + 4096;                         // f32 [8][256] inv row-sum-exp
static constexpr size_t oPS    = oISE  + 8192;                         // f32 [256][8][256] rowsum partials
static constexpr size_t oCTX   = oPS   + (size_t)256 * 2048 * 4;       // (unused now)
static constexpr size_t oMB    = oCTX  + (size_t)64 * 1024 * 4;        // bf16 [8][256][256]
static constexpr size_t oCPART = oMB   + (size_t)8 * 256 * 256 * 2;    // f32 [4096][1024]
static constexpr size_t oMPART = oCPART + (size_t)4096 * 1024 * 4;     // f32 [8][8][HW]

DEVI float bf2f(short x) {
  unsigned u = ((unsigned)(unsigned short)x) << 16;
  return __builtin_bit_cast(float, u);
}
DEVI u16 f2bf(float x) { return __builtin_bit_cast(u16, (__bf16)x); }

DEVI void gld16(const void* g, void* l) {
  __builtin_amdgcn_global_load_lds(
      (__attribute__((address_space(1))) void*)(g),
      (__attribute__((address_space(3))) void*)(l), 16, 0, 0);
}

// ---------------- fused: transpose x -> xbT (blocks 0..2047) | pack W/bias (blocks 2048..2111) ----------------
__global__ __launch_bounds__(256) void k_pt(
    const float* __restrict__ x,
    const float* __restrict__ Wk, const float* __restrict__ Wq, const float* __restrict__ Wv,
    const float* __restrict__ bk, const float* __restrict__ bq, const float* __restrict__ bv,
    u16* __restrict__ xbT, u16* __restrict__ Wkqv, float* __restrict__ bias)
{
  __shared__ u16 lds[64 * 256];
  const int t = threadIdx.x;
  const int tb = blockIdx.x;
  if (tb < 2048) {
    const int n = tb >> 8;
    const int s0 = (tb & 255) * 64;
    const float* src = x + ((size_t)n * 256 + t) * HW + s0;
    #pragma unroll
    for (int i = 0; i < 16; ++i) {
      f32x4 v = *(const f32x4*)(src + i * 4);
      #pragma unroll
      for (int j = 0; j < 4; ++j) lds[(i * 4 + j) * 256 + t] = f2bf(v[j]);
    }
    __syncthreads();
    s16x8* gp = (s16x8*)(xbT + (size_t)n * BSTRIDE + (size_t)s0 * 256);
    const s16x8* lp = (const s16x8*)lds;
    #pragma unroll
    for (int i = 0; i < 8; ++i) gp[t + i * 256] = lp[t + i * 256];
  } else {
    const int i = (tb - 2048) * 256 + t;
    for (int p = i; p < 768 * 256; p += 64 * 256) {
      float v = (p < 65536) ? Wk[p] : (p < 131072 ? Wq[p - 65536] : Wv[p - 131072]);
      Wkqv[p] = f2bf(v);
    }
    if (i < 768) bias[i] = (i < 256) ? bk[i] : (i < 512 ? bq[i - 256] : bv[i - 512]);
  }
}

// ======== r7/r9 single-tile core (queries role) ========
#define GEMM_CORE(Ab, Bb)                                                                   \
  u16* Al = smem;                                                                           \
  u16* Bl = smem + 16384;                                                                   \
  auto STAGE = [&](int buf, int kt) {                                                       \
    const int k0 = kt * 64;                                                                 \
    _Pragma("unroll")                                                                       \
    for (int i = 0; i < 4; ++i) {                                                           \
      const int r_ = i * 32 + (t >> 3);                                                     \
      const int cs = (((t & 7) ^ (r_ & 7)) * 8);                                            \
      gld16((Ab) + (size_t)r_ * 256 + k0 + cs, Al + buf * 8192 + i * 2048 + t * 8);         \
      gld16((Bb) + (size_t)r_ * 256 + k0 + cs, Bl + buf * 8192 + i * 2048 + t * 8);         \
    }                                                                                       \
  };                                                                                        \
  f32x4 acc[4][4] = {};                                                                     \
  STAGE(0, 0); STAGE(1, 1);                                                                 \
  _Pragma("unroll")                                                                         \
  for (int kt = 0; kt < 4; ++kt) {                                                          \
    if (kt < 3) asm volatile("s_waitcnt vmcnt(8)" ::: "memory");                            \
    else        asm volatile("s_waitcnt vmcnt(0)" ::: "memory");                            \
    __builtin_amdgcn_s_barrier();                                                           \
    const int buf = kt & 1;                                                                 \
    _Pragma("unroll")                                                                       \
    for (int ks = 0; ks < 2; ++ks) {                                                        \
      bf16x8 af[4], bff[4];                                                                 \
      _Pragma("unroll")                                                                     \
      for (int g = 0; g < 4; ++g) {                                                         \
        const int mrow = wm + g * 16 + l15;                                                 \
        const int srow = wn + g * 16 + l15;                                                 \
        af[g]  = *(const bf16x8*)&Al[buf * 8192 + mrow * 64 + (((ks * 4 + l4) ^ (mrow & 7)) * 8)]; \
        bff[g] = *(const bf16x8*)&Bl[buf * 8192 + srow * 64 + (((ks * 4 + l4) ^ (srow & 7)) * 8)]; \
      }                                                                                     \
      __builtin_amdgcn_s_setprio(1);                                                        \
      _Pragma("unroll")                                                                     \
      for (int mg = 0; mg < 4; ++mg)                                                        \
        _Pragma("unroll")                                                                   \
        for (int ng = 0; ng < 4; ++ng)                                                      \
          acc[mg][ng] = __builtin_amdgcn_mfma_f32_16x16x32_bf16(af[mg], bff[ng], acc[mg][ng], 0, 0, 0); \
      __builtin_amdgcn_s_setprio(0);                                                        \
    }                                                                                       \
    asm volatile("s_waitcnt lgkmcnt(0)" ::: "memory");                                      \
    __builtin_amdgcn_s_barrier();                                                           \
    if (kt < 2) STAGE(buf, kt + 2);                                                         \
  }

// ---------------- merged projections: KV multi-tile (idx<128) | Q single-tile (idx>=128) ----------------
__global__ __launch_bounds__(256, 2) void k_proj(
    const u16* __restrict__ W, const u16* __restrict__ xbT, const float* __restrict__ bias,
    u16* __restrict__ ek, u16* __restrict__ qT, u16* __restrict__ vb, float* __restrict__ ps)
{
  __shared__ u16 smem[32768];          // 64 KiB
  const int t = threadIdx.x;
  const int L = blockIdx.x;
  const int n = L & 7;                 // batch == XCD
  const int idx = L >> 3;              // 0..383
  const int lane = t & 63;
  const int l15 = lane & 15, l4 = (lane >> 4) & 3;
  const int wv = t >> 6;
  const int wm = (wv & 1) * 64, wn = (wv >> 1) * 64;

  if (idx < 128) {
    // ======== keys+values multi-tile (r9-verbatim) ========
    const int mbi = idx & 3;
    const int sq  = idx >> 2;          // 0..31
    const bool isK = (mbi < 2);
    const int m0 = (mbi & 1) * 128;
    const int aBase = (isK ? 0 : 512) + m0;
    const u16* Ab = W + (size_t)aBase * 256;
    const u16* Bb = xbT + (size_t)n * BSTRIDE;
    u16* Al = smem;
    u16* Bl = smem + 16384;

    float biasv[4];
    #pragma unroll
    for (int mf = 0; mf < 4; ++mf) biasv[mf] = bias[aBase + wm + mf * 16 + l15];

    const int rr = t >> 3;
    const int csh = t & 7;
    auto STAGE = [&](int buf, int it) {
      const int k0 = (it & 3) * 64;
      const size_t s_t0 = (size_t)((sq * 4 + (it >> 2)) * 128);
      #pragma unroll
      for (int i = 0; i < 4; ++i) {
        const int row = i * 32 + rr;
        const int cs = (csh ^ (row & 7)) * 8;
        gld16(Ab + (size_t)row * 256 + k0 + cs,  Al + buf * 8192 + i * 2048 + t * 8);
        gld16(Bb + (s_t0 + row) * 256 + k0 + cs, Bl + buf * 8192 + i * 2048 + t * 8);
      }
    };

    f32x4 acc[4][4] = {};
    STAGE(0, 0); STAGE(1, 1);
    u16* outb = (isK ? ek : vb) + (size_t)n * BSTRIDE;

    #pragma unroll
    for (int it = 0; it < 16; ++it) {
      if (it == 15)                          asm volatile("s_waitcnt vmcnt(0)" ::: "memory");
      else if ((it & 3) <= 1 && it >= 4) {
        if (isK) asm volatile("s_waitcnt vmcnt(28)" ::: "memory");
        else     asm volatile("s_waitcnt vmcnt(24)" ::: "memory");
      } else                                 asm volatile("s_waitcnt vmcnt(8)" ::: "memory");
      __builtin_amdgcn_s_barrier();

      const int buf = it & 1;
      #pragma unroll
      for (int ks = 0; ks < 2; ++ks) {
        bf16x8 af[4], bff[4];
        #pragma unroll
        for (int g = 0; g < 4; ++g) {
          const int mrow = wm + g * 16 + l15;
          const int srow = wn + g * 16 + l15;
          af[g]  = *(const bf16x8*)&Al[buf * 8192 + mrow * 64 + (((ks * 4 + l4) ^ (mrow & 7)) * 8)];
          bff[g] = *(const bf16x8*)&Bl[buf * 8192 + srow * 64 + (((ks * 4 + l4) ^ (srow & 7)) * 8)];
        }
        __builtin_amdgcn_s_setprio(1);
        #pragma unroll
        for (int sf = 0; sf < 4; ++sf)
          #pragma unroll
          for (int mf = 0; mf < 4; ++mf)
            acc[sf][mf] = __builtin_amdgcn_mfma_f32_16x16x32_bf16(bff[sf], af[mf], acc[sf][mf], 0, 0, 0);
        __builtin_amdgcn_s_setprio(0);
      }
      asm volatile("s_waitcnt lgkmcnt(0)" ::: "memory");
      __builtin_amdgcn_s_barrier();
      if (it < 14) STAGE(buf, it + 2);

      if ((it & 3) == 3) {
        const int tile = it >> 2;
        const int s0t = (sq * 4 + tile) * 128;
        const int stile = sq * 4 + tile;
        if (isK) {
          float rs[4] = {0.f, 0.f, 0.f, 0.f};
          #pragma unroll
          for (int sf = 0; sf < 4; ++sf)
            #pragma unroll
            for (int mf = 0; mf < 4; ++mf) {
              s16x4 pk;
              #pragma unroll
              for (int r = 0; r < 4; ++r) {
                const float e = __expf(acc[sf][mf][r] + biasv[mf]);
                rs[mf] += e;
                pk[r] = (short)f2bf(e);
              }
              *(s16x4*)(outb + (size_t)(m0 + wm + mf * 16 + l15) * HW + s0t + wn + sf * 16 + l4 * 4) = pk;
            }
          #pragma unroll
          for (int mf = 0; mf < 4; ++mf) {
            float v = rs[mf];
            v += __shfl_xor(v, 16); v += __shfl_xor(v, 32);
            if (l4 == 0)
              ps[((size_t)(stile * 2 + (wn >> 6))) * 2048 + n * 256 + m0 + wm + mf * 16 + l15] = v;
          }
        } else {
          #pragma unroll
          for (int sf = 0; sf < 4; ++sf)
            #pragma unroll
            for (int mf = 0; mf < 4; ++mf) {
              s16x4 pk;
              #pragma unroll
              for (int r = 0; r < 4; ++r) pk[r] = (short)f2bf(acc[sf][mf][r] + biasv[mf]);
              *(s16x4*)(outb + (size_t)(m0 + wm + mf * 16 + l15) * HW + s0t + wn + sf * 16 + l4 * 4) = pk;
            }
        }
        #pragma unroll
        for (int sf = 0; sf < 4; ++sf)
          #pragma unroll
          for (int mf = 0; mf < 4; ++mf) acc[sf][mf] = f32x4{0.f, 0.f, 0.f, 0.f};
      }
    }
  } else {
    // ======== queries single-tile (r9-verbatim) ========
    const int qidx = idx - 128;        // 0..255
    const int mbq = qidx & 1;
    const int sb  = qidx >> 1;         // 0..127
    const int m0 = 256 + mbq * 128, s0 = sb * 128;
    const u16* Ab = W + (size_t)m0 * 256;
    const u16* Bb = xbT + (size_t)n * BSTRIDE + (size_t)s0 * 256;

    GEMM_CORE(Ab, Bb)

    #pragma unroll
    for (int mg = 0; mg < 4; ++mg)
      #pragma unroll
      for (int r = 0; r < 4; ++r) {
        const float bb = bias[m0 + wm + mg * 16 + l4 * 4 + r];
        #pragma unroll
        for (int ng = 0; ng < 4; ++ng) acc[mg][ng][r] += bb;
      }

    #pragma unroll
    for (int hh = 0; hh < 2; ++hh)
      #pragma unroll
      for (int ng = 0; ng < 4; ++ng) {
        float s = 0.f;
        #pragma unroll
        for (int mg = hh * 2; mg < hh * 2 + 2; ++mg)
          #pragma unroll
          for (int r = 0; r < 4; ++r) { const float e = __expf(acc[mg][ng][r]); acc[mg][ng][r] = e; s += e; }
        s += __shfl_xor(s, 16);
        s += __shfl_xor(s, 32);
        const float inv = 1.f / s;
        #pragma unroll
        for (int mg = hh * 2; mg < hh * 2 + 2; ++mg)
          #pragma unroll
          for (int r = 0; r < 4; ++r) acc[mg][ng][r] *= inv;
      }
    __syncthreads();
    #pragma unroll
    for (int mg = 0; mg < 4; ++mg)
      #pragma unroll
      for (int ng = 0; ng < 4; ++ng)
        #pragma unroll
        for (int r = 0; r < 4; ++r) {
          const int srow = wn + ng * 16 + l15;
          const int mcol = wm + mg * 16 + l4 * 4 + r;
          smem[srow * 136 + mcol] = f2bf(acc[mg][ng][r]);
        }
    __syncthreads();
    u16* O = qT + (size_t)n * BSTRIDE + (size_t)s0 * 256 + mbq * 128;
    #pragma unroll
    for (int it = 0; it < 8; ++it) {
      const int row = it * 16 + (t >> 4);
      *(s16x8*)(O + (size_t)row * 256 + (t & 15) * 8) = *(const s16x8*)&smem[row * 136 + (t & 15) * 8];
    }
  }
}

// ---------------- reduce rowsum partials -> inverse ----------------
__global__ __launch_bounds__(256) void k_inv(const float* __restrict__ ps, float* __restrict__ ise)
{
  const int i = blockIdx.x * 256 + threadIdx.x;   // 2048
  float s = 0.f;
  for (int b = 0; b < 256; ++b) s += ps[(size_t)b * 2048 + i];
  ise[i] = 1.f / s;
}

// ---------------- ctx split-K partials + fused attention-map partials ----------------
__global__ __launch_bounds__(64) void k_ctx_part(
    const u16* __restrict__ ek, const u16* __restrict__ vb, const float* __restrict__ ise,
    float* __restrict__ cpart, float* __restrict__ mpart)
{
  const int blk = blockIdx.x;            // nh*64 + chunk
  const int chunk = blk & 63, nh = blk >> 6;
  const int h = nh & 7, n = nh >> 3;
  const int lane = threadIdx.x;
  const int l15 = lane & 15, l4 = lane >> 4;
  const u16* kb = ek + ((size_t)n * 256 + h * 32) * HW;
  const u16* vv = vb + ((size_t)n * 256 + h * 32) * HW;
  const float iv0 = ise[n * 256 + h * 32 + l15];
  const float iv1 = ise[n * 256 + h * 32 + 16 + l15];
  f32x4 acc[2][2] = {};
  float macc[8][8] = {};
  const int sbase = chunk * 256 + l4 * 8;
  #pragma unroll
  for (int ks = 0; ks < 8; ++ks) {
    const int sb = sbase + ks * 32;
    bf16x8 ef[2], vf[2];
    #pragma unroll
    for (int g = 0; g < 2; ++g) {
      ef[g] = *(const bf16x8*)(kb + (size_t)(g * 16 + l15) * HW + sb);
      vf[g] = *(const bf16x8*)(vv + (size_t)(g * 16 + l15) * HW + sb);
    }
    #pragma unroll
    for (int j = 0; j < 8; ++j)
      macc[ks][j] = fmaf(iv0, (float)ef[0][j], fmaf(iv1, (float)ef[1][j], macc[ks][j]));
    #pragma unroll
    for (int a = 0; a < 2; ++a)
      #pragma unroll
      for (int b = 0; b < 2; ++b)
        acc[a][b] = __builtin_amdgcn_mfma_f32_16x16x32_bf16(ef[a], vf[b], acc[a][b], 0, 0, 0);
  }
  float* op = cpart + (size_t)blk * 1024;
  #pragma unroll
  for (int a = 0; a < 2; ++a)
    #pragma unroll
    for (int b = 0; b < 2; ++b)
      #pragma unroll
      for (int r = 0; r < 4; ++r)
        op[(a * 16 + l4 * 4 + r) * 32 + b * 16 + l15] = acc[a][b][r];
  #pragma unroll
  for (int ks = 0; ks < 8; ++ks)
    #pragma unroll
    for (int j = 0; j < 8; ++j) {
      float v = macc[ks][j];
      v += __shfl_xor(v, 1); v += __shfl_xor(v, 2);
      v += __shfl_xor(v, 4); v += __shfl_xor(v, 8);
      macc[ks][j] = v;
    }
  if (l15 == 0) {
    float* mp = mpart + ((size_t)h * 8 + n) * HW + sbase;
    #pragma unroll
    for (int ks = 0; ks < 8; ++ks) {
      f32x4 a = {macc[ks][0], macc[ks][1], macc[ks][2], macc[ks][3]};
      f32x4 b = {macc[ks][4], macc[ks][5], macc[ks][6], macc[ks][7]};
      *(f32x4*)(mp + ks * 32)     = a;
      *(f32x4*)(mp + ks * 32 + 4) = b;
    }
  }
}

// ---------------- fused post: blocks 0..63 = ctx_reduce+mmat (LDS handoff) ; 64..191 = map_reduce ----------------
__global__ __launch_bounds__(256) void k_post(
    const float* __restrict__ cpart, const float* __restrict__ ise,
    const float* __restrict__ Wr, const float* __restrict__ mpart,
    u16* __restrict__ Mb, float* __restrict__ dctx, float* __restrict__ dmap)
{
  const int t = threadIdx.x;
  if (blockIdx.x < 64) {
    const int nh = blockIdx.x, n = nh >> 3, h = nh & 7;
    __shared__ float cl[1024];
    f32x4 a = {};
    for (int c = 0; c < 64; ++c) a += *(const f32x4*)(cpart + ((size_t)nh * 64 + c) * 1024 + t * 4);
    const float inv = ise[n * 256 + h * 32 + (t >> 3)];
    a *= inv;
    *(f32x4*)(cl + t * 4) = a;
    if (h == 7) *(f32x4*)(dctx + (size_t)n * 1024 + t * 4) = a;
    __syncthreads();
    // mmat: M[n][o][h*32+k] = sum_v Wr[o][h*32+v] * cl[k*32+v]
    const int o = t;
    float wr[32];
    const float* wp = Wr + (size_t)o * 256 + h * 32;
    #pragma unroll
    for (int v = 0; v < 32; ++v) wr[v] = wp[v];
    u16* mp = Mb + ((size_t)n * 256 + o) * 256 + h * 32;
    #pragma unroll 4
    for (int k = 0; k < 32; ++k) {
      float s = 0.f;
      #pragma unroll
      for (int v = 0; v < 32; ++v) s += wr[v] * cl[k * 32 + v];
      mp[k] = f2bf(s);
    }
  } else {
    const int i = (blockIdx.x - 64) * 256 + t;   // 32768 threads, f32x4 each
    f32x4 a = {};
    #pragma unroll
    for (int h = 0; h < 8; ++h) a += *(const f32x4*)(mpart + (size_t)h * 131072 + (size_t)i * 4);
    a *= (1.0f / 256.0f);
    *(f32x4*)(dmap + (size_t)i * 4) = a;
  }
}

// ---------------- final GEMM multi-tile (r9-verbatim): attn[o][s] = M·Q^T + br, f32 ----------------
__global__ __launch_bounds__(256, 2) void k_attn2(
    const u16* __restrict__ Mb, const u16* __restrict__ qT, const float* __restrict__ br,
    float* __restrict__ Out)
{
  __shared__ u16 smem[32768];
  const int t = threadIdx.x;
  const int L = blockIdx.x;
  const int n = L & 7;
  const int idx = L >> 3;
  const int mb = idx & 1;
  const int sq = idx >> 1;
  const int m0 = mb * 128;
  const int lane = t & 63;
  const int l15 = lane & 15, l4 = (lane >> 4) & 3;
  const int wv = t >> 6;
  const int wm = (wv & 1) * 64, wn = (wv >> 1) * 64;
  const u16* Ab = Mb + (size_t)n * 65536 + (size_t)m0 * 256;
  const u16* Bb = qT + (size_t)n * BSTRIDE;
  u16* Al = smem;
  u16* Bl = smem + 16384;

  float biasv[4];
  #pragma unroll
  for (int mf = 0; mf < 4; ++mf) biasv[mf] = br[m0 + wm + mf * 16 + l15];

  const int rr = t >> 3;
  const int csh = t & 7;
  auto STAGE = [&](int buf, int it) {
    const int k0 = (it & 3) * 64;
    const size_t s_t0 = (size_t)((sq * 4 + (it >> 2)) * 128);
    #pragma unroll
    for (int i = 0; i < 4; ++i) {
      const int row = i * 32 + rr;
      const int cs = (csh ^ (row & 7)) * 8;
      gld16(Ab + (size_t)row * 256 + k0 + cs,  Al + buf * 8192 + i * 2048 + t * 8);
      gld16(Bb + (s_t0 + row) * 256 + k0 + cs, Bl + buf * 8192 + i * 2048 + t * 8);
    }
  };

  f32x4 acc[4][4] = {};
  STAGE(0, 0); STAGE(1, 1);

  float* ob = Out + (size_t)n * BSTRIDE;

  #pragma unroll
  for (int it = 0; it < 16; ++it) {
    if (it == 15)                          asm volatile("s_waitcnt vmcnt(0)" ::: "memory");
    else if ((it & 3) <= 1 && it >= 4)     asm volatile("s_waitcnt vmcnt(24)" ::: "memory");
    else                                   asm volatile("s_waitcnt vmcnt(8)" ::: "memory");
    __builtin_amdgcn_s_barrier();

    const int buf = it & 1;
    #pragma unroll
    for (int ks = 0; ks < 2; ++ks) {
      bf16x8 af[4], bff[4];
      #pragma unroll
      for (int g = 0; g < 4; ++g) {
        const int mrow = wm + g * 16 + l15;
        const int srow = wn + g * 16 + l15;
        af[g]  = *(const bf16x8*)&Al[buf * 8192 + mrow * 64 + (((ks * 4 + l4) ^ (mrow & 7)) * 8)];
        bff[g] = *(const bf16x8*)&Bl[buf * 8192 + srow * 64 + (((ks * 4 + l4) ^ (srow & 7)) * 8)];
      }
      __builtin_amdgcn_s_setprio(1);
      #pragma unroll
      for (int sf = 0; sf < 4; ++sf)
        #pragma unroll
        for (int mf = 0; mf < 4; ++mf)
          acc[sf][mf] = __builtin_amdgcn_mfma_f32_16x16x32_bf16(bff[sf], af[mf], acc[sf][mf], 0, 0, 0);
      __builtin_amdgcn_s_setprio(0);
    }
    asm volatile("s_waitcnt lgkmcnt(0)" ::: "memory");
    __builtin_amdgcn_s_barrier();
    if (it < 14) STAGE(buf, it + 2);

    if ((it & 3) == 3) {
      const int s0t = (sq * 4 + (it >> 2)) * 128;
      #pragma unroll
      for (int sf = 0; sf < 4; ++sf)
        #pragma unroll
        for (int mf = 0; mf < 4; ++mf) {
          f32x4 o = acc[sf][mf] + biasv[mf];
          *(f32x4*)(ob + (size_t)(m0 + wm + mf * 16 + l15) * HW + s0t + wn + sf * 16 + l4 * 4) = o;
          acc[sf][mf] = f32x4{0.f, 0.f, 0.f, 0.f};
        }
    }
  }
}

extern "C" void kernel_launch(void* const* d_in, const int* in_sizes, int n_in,
                              void* d_out, int out_size, void* d_ws, size_t ws_size,
                              hipStream_t stream)
{
  (void)in_sizes; (void)n_in; (void)out_size; (void)ws_size;
  const float* x  = (const float*)d_in[0];
  const float* Wk = (const float*)d_in[1];
  const float* bk = (const float*)d_in[2];
  const float* Wq = (const float*)d_in[3];
  const float* bq = (const float*)d_in[4];
  const float* Wv = (const float*)d_in[5];
  const float* bv = (const float*)d_in[6];
  const float* Wr = (const float*)d_in[7];
  const float* br = (const float*)d_in[8];

  char* ws = (char*)d_ws;
  u16*   xbT  = (u16*)(ws + oXBT);
  u16*   ek   = (u16*)(ws + oEK);
  u16*   qT   = (u16*)(ws + oQT);
  u16*   vb   = (u16*)(ws + oVB);
  u16*   Wkqv = (u16*)(ws + oWK);
  float* bias = (float*)(ws + oBIAS);
  float* ise  = (float*)(ws + oISE);
  float* ps   = (float*)(ws + oPS);
  u16*   Mb   = (u16*)(ws + oMB);
  float* cpart= (float*)(ws + oCPART);
  float* mpart= (float*)(ws + oMPART);

  float* attn = (float*)d_out;                    // [8][256][HW]
  float* dctx = (float*)d_out + 33554432;         // [8][32][32]
  float* dmap = (float*)d_out + 33562624;         // [8][HW]

  k_pt<<<2112, 256, 0, stream>>>(x, Wk, Wq, Wv, bk, bq, bv, xbT, Wkqv, bias);
  k_proj<<<3072, 256, 0, stream>>>(Wkqv, xbT, bias, ek, qT, vb, ps);
  k_inv<<<8, 256, 0, stream>>>(ps, ise);
  k_ctx_part<<<4096, 64, 0, stream>>>(ek, vb, ise, cpart, mpart);
  k_post<<<192, 256, 0, stream>>>(cpart, ise, Wr, mpart, Mb, dctx, dmap);
  k_attn2<<<512, 256, 0, stream>>>(Mb, qT, br, attn);
}

// Round 13
// 274.267 us; speedup vs baseline: 1.6124x; 1.0348x over previous
//
#include <hip/hip_runtime.h>
#include <hip/hip_bf16.h>

typedef float f32x4 __attribute__((ext_vector_type(4)));
typedef short s16x8 __attribute__((ext_vector_type(8)));
typedef short s16x4 __attribute__((ext_vector_type(4)));
typedef __bf16 bf16x8 __attribute__((ext_vector_type(8)));
typedef unsigned short u16;

#define DEVI __device__ __forceinline__

static constexpr int    HW      = 16384;
static constexpr size_t BSTRIDE = (size_t)256 * HW;

// ---- workspace byte offsets ----
static constexpr size_t oXBT   = 0;                                    // bf16 [8][HW][256]
static constexpr size_t oEK    = oXBT  + (size_t)8 * HW * 256 * 2;     // bf16 [8][256][HW] exp(keys)
static constexpr size_t oQT    = oEK   + (size_t)8 * 256 * HW * 2;     // bf16 [8][HW][256] softmaxed Q, transposed
static constexpr size_t oVB    = oQT   + (size_t)8 * HW * 256 * 2;     // bf16 [8][256][HW]
static constexpr size_t oWK    = oVB   + (size_t)8 * 256 * HW * 2;     // bf16 [768][256]
static constexpr size_t oBIAS  = oWK   + (size_t)768 * 256 * 2;        // f32 [768]
static constexpr size_t oISE   = oBIAS + 4096;                         // f32 [8][256] inv row-sum-exp
static constexpr size_t oPS    = oISE  + 8192;                         // f32 [256][8][256] rowsum partials
static constexpr size_t oCTX   = oPS   + (size_t)256 * 2048 * 4;       // (unused)
static constexpr size_t oMB    = oCTX  + (size_t)64 * 1024 * 4;        // bf16 [8][256][256]
static constexpr size_t oCPART = oMB   + (size_t)8 * 256 * 256 * 2;    // f32 [4096][1024]
static constexpr size_t oMPART = oCPART + (size_t)4096 * 1024 * 4;     // f32 [8][8][HW]

DEVI float bf2f(short x) {
  unsigned u = ((unsigned)(unsigned short)x) << 16;
  return __builtin_bit_cast(float, u);
}
DEVI u16 f2bf(float x) { return __builtin_bit_cast(u16, (__bf16)x); }

DEVI void gld16(const void* g, void* l) {
  __builtin_amdgcn_global_load_lds(
      (__attribute__((address_space(1))) void*)(g),
      (__attribute__((address_space(3))) void*)(l), 16, 0, 0);
}

// ---------------- fused: transpose x -> xbT (blocks 0..2047) | pack W/bias (blocks 2048..2111) ----------------
__global__ __launch_bounds__(256) void k_pt(
    const float* __restrict__ x,
    const float* __restrict__ Wk, const float* __restrict__ Wq, const float* __restrict__ Wv,
    const float* __restrict__ bk, const float* __restrict__ bq, const float* __restrict__ bv,
    u16* __restrict__ xbT, u16* __restrict__ Wkqv, float* __restrict__ bias)
{
  __shared__ u16 lds[64 * 256];
  const int t = threadIdx.x;
  const int tb = blockIdx.x;
  if (tb < 2048) {
    const int n = tb >> 8;
    const int s0 = (tb & 255) * 64;
    const float* src = x + ((size_t)n * 256 + t) * HW + s0;
    #pragma unroll
    for (int i = 0; i < 16; ++i) {
      f32x4 v = *(const f32x4*)(src + i * 4);
      #pragma unroll
      for (int j = 0; j < 4; ++j) lds[(i * 4 + j) * 256 + t] = f2bf(v[j]);
    }
    __syncthreads();
    s16x8* gp = (s16x8*)(xbT + (size_t)n * BSTRIDE + (size_t)s0 * 256);
    const s16x8* lp = (const s16x8*)lds;
    #pragma unroll
    for (int i = 0; i < 8; ++i) gp[t + i * 256] = lp[t + i * 256];
  } else {
    const int i = (tb - 2048) * 256 + t;
    for (int p = i; p < 768 * 256; p += 64 * 256) {
      float v = (p < 65536) ? Wk[p] : (p < 131072 ? Wq[p - 65536] : Wv[p - 131072]);
      Wkqv[p] = f2bf(v);
    }
    if (i < 768) bias[i] = (i < 256) ? bk[i] : (i < 512 ? bq[i - 256] : bv[i - 512]);
  }
}

// ================= B-resident 3-operator projection GEMM =================
// Block = (n, mh, sb): B-panel [128 s][256 k] staged ONCE into LDS (64KB, swizzled);
// ops K (g0-7, swapped), V (g8-15, swapped), Q (g16-23, unswapped) stream tiny A-tiles
// through a 16KB double-buffer. Q epilogue reuses dead B region for the r7 overlay transpose.
__global__ __launch_bounds__(256, 2) void k_proj3(
    const u16* __restrict__ W, const u16* __restrict__ xbT, const float* __restrict__ bias,
    u16* __restrict__ ek, u16* __restrict__ qT, u16* __restrict__ vb, float* __restrict__ ps)
{
  __shared__ u16 smem[40960];          // B [0,32768) u16 ; A dbuf [32768,40960)
  const int t = threadIdx.x;
  const int L = blockIdx.x;
  const int n = L & 7;                 // batch == XCD
  const int idx = L >> 3;              // 0..255
  const int mh = idx & 1;
  const int sb = idx >> 1;             // 0..127
  const int m0 = mh * 128;
  const int s0 = sb * 128;
  const int lane = t & 63;
  const int l15 = lane & 15, l4 = (lane >> 4) & 3;
  const int wv = t >> 6;
  const int wm = (wv & 1) * 64, wn = (wv >> 1) * 64;

  const u16* Bb = xbT + (size_t)n * BSTRIDE + (size_t)s0 * 256;

  float bK[4], bV[4];
  #pragma unroll
  for (int mf = 0; mf < 4; ++mf) {
    bK[mf] = bias[m0 + wm + mf * 16 + l15];
    bV[mf] = bias[512 + m0 + wm + mf * 16 + l15];
  }

  // ---- B prologue: 16 gld16/thread, linear LDS dest, pre-swizzled source (rule #21) ----
  #pragma unroll
  for (int i = 0; i < 16; ++i) {
    const int f = i * 256 + t;
    const int row = f >> 5, c = f & 31;
    gld16(Bb + (size_t)row * 256 + ((c ^ (row & 7)) * 8), smem + f * 8);
  }

  auto STAGEA = [&](int g) {
    const int kt = g & 7;
    const int op = g >> 3;
    const int wr0 = (op == 0) ? 0 : (op == 1 ? 512 : 256);
    const u16* Ab = W + (size_t)(wr0 + m0) * 256;
    #pragma unroll
    for (int i = 0; i < 2; ++i) {
      const int f = i * 256 + t;
      const int row = f >> 2, c = f & 3;
      gld16(Ab + (size_t)row * 256 + kt * 32 + ((c ^ (row & 3)) * 8),
            smem + 32768 + (g & 1) * 4096 + f * 8);
    }
  };

  STAGEA(0); STAGEA(1);

  f32x4 acc[4][4] = {};
  u16* ekb = ek + (size_t)n * BSTRIDE;
  u16* vbb = vb + (size_t)n * BSTRIDE;

  #pragma unroll
  for (int g = 0; g < 24; ++g) {
    // gate: B + A(g) resident; A(g+1) may stay in flight. In-order VMEM retirement makes
    // vmcnt(2) correct even with older epilogue stores in the queue.
    if (g == 23) asm volatile("s_waitcnt vmcnt(0)" ::: "memory");
    else         asm volatile("s_waitcnt vmcnt(2)" ::: "memory");
    __builtin_amdgcn_s_barrier();

    const int kt = g & 7;
    bf16x8 af[4], bff[4];
    #pragma unroll
    for (int gg = 0; gg < 4; ++gg) {
      const int mrow = wm + gg * 16 + l15;
      const int srow = wn + gg * 16 + l15;
      const int cidx = kt * 4 + l4;
      af[gg]  = *(const bf16x8*)&smem[32768 + (g & 1) * 4096 + mrow * 32 + ((l4 ^ (mrow & 3)) * 8)];
      bff[gg] = *(const bf16x8*)&smem[srow * 256 + ((cidx ^ (srow & 7)) * 8)];
    }
    __builtin_amdgcn_s_setprio(1);
    if (g < 16) {
      #pragma unroll
      for (int sf = 0; sf < 4; ++sf)
        #pragma unroll
        for (int mf = 0; mf < 4; ++mf)
          acc[sf][mf] = __builtin_amdgcn_mfma_f32_16x16x32_bf16(bff[sf], af[mf], acc[sf][mf], 0, 0, 0);
    } else {
      #pragma unroll
      for (int mg = 0; mg < 4; ++mg)
        #pragma unroll
        for (int ng = 0; ng < 4; ++ng)
          acc[mg][ng] = __builtin_amdgcn_mfma_f32_16x16x32_bf16(af[mg], bff[ng], acc[mg][ng], 0, 0, 0);
    }
    __builtin_amdgcn_s_setprio(0);

    asm volatile("s_waitcnt lgkmcnt(0)" ::: "memory");   // frag reads of Abuf retired
    __builtin_amdgcn_s_barrier();
    if (g < 22) STAGEA(g + 2);

    if (g == 7) {
      // ---- keys epilogue (swapped layout, r12-verbatim math) ----
      float rs[4] = {0.f, 0.f, 0.f, 0.f};
      #pragma unroll
      for (int sf = 0; sf < 4; ++sf)
        #pragma unroll
        for (int mf = 0; mf < 4; ++mf) {
          s16x4 pk;
          #pragma unroll
          for (int r = 0; r < 4; ++r) {
            const float e = __expf(acc[sf][mf][r] + bK[mf]);
            rs[mf] += e;
            pk[r] = (short)f2bf(e);
          }
          *(s16x4*)(ekb + (size_t)(m0 + wm + mf * 16 + l15) * HW + s0 + wn + sf * 16 + l4 * 4) = pk;
        }
      #pragma unroll
      for (int mf = 0; mf < 4; ++mf) {
        float v = rs[mf];
        v += __shfl_xor(v, 16); v += __shfl_xor(v, 32);
        if (l4 == 0)
          ps[((size_t)(sb * 2 + (wn >> 6))) * 2048 + n * 256 + m0 + wm + mf * 16 + l15] = v;
      }
      #pragma unroll
      for (int sf = 0; sf < 4; ++sf)
        #pragma unroll
        for (int mf = 0; mf < 4; ++mf) acc[sf][mf] = f32x4{0.f, 0.f, 0.f, 0.f};
    } else if (g == 15) {
      // ---- values epilogue ----
      #pragma unroll
      for (int sf = 0; sf < 4; ++sf)
        #pragma unroll
        for (int mf = 0; mf < 4; ++mf) {
          s16x4 pk;
          #pragma unroll
          for (int r = 0; r < 4; ++r) pk[r] = (short)f2bf(acc[sf][mf][r] + bV[mf]);
          *(s16x4*)(vbb + (size_t)(m0 + wm + mf * 16 + l15) * HW + s0 + wn + sf * 16 + l4 * 4) = pk;
        }
      #pragma unroll
      for (int sf = 0; sf < 4; ++sf)
        #pragma unroll
        for (int mf = 0; mf < 4; ++mf) acc[sf][mf] = f32x4{0.f, 0.f, 0.f, 0.f};
    }
  }

  // ---- Q epilogue (unswapped layout; r7 overlay transpose in dead B region) ----
  #pragma unroll
  for (int mg = 0; mg < 4; ++mg)
    #pragma unroll
    for (int r = 0; r < 4; ++r) {
      const float bb = bias[256 + m0 + wm + mg * 16 + l4 * 4 + r];
      #pragma unroll
      for (int ng = 0; ng < 4; ++ng) acc[mg][ng][r] += bb;
    }
  #pragma unroll
  for (int hh = 0; hh < 2; ++hh)
    #pragma unroll
    for (int ng = 0; ng < 4; ++ng) {
      float s = 0.f;
      #pragma unroll
      for (int mg = hh * 2; mg < hh * 2 + 2; ++mg)
        #pragma unroll
        for (int r = 0; r < 4; ++r) { const float e = __expf(acc[mg][ng][r]); acc[mg][ng][r] = e; s += e; }
      s += __shfl_xor(s, 16);
      s += __shfl_xor(s, 32);
      const float inv = 1.f / s;
      #pragma unroll
      for (int mg = hh * 2; mg < hh * 2 + 2; ++mg)
        #pragma unroll
        for (int r = 0; r < 4; ++r) acc[mg][ng][r] *= inv;
    }
  __syncthreads();
  #pragma unroll
  for (int mg = 0; mg < 4; ++mg)
    #pragma unroll
    for (int ng = 0; ng < 4; ++ng)
      #pragma unroll
      for (int r = 0; r < 4; ++r) {
        const int srow = wn + ng * 16 + l15;
        const int mcol = wm + mg * 16 + l4 * 4 + r;
        smem[srow * 136 + mcol] = f2bf(acc[mg][ng][r]);
      }
  __syncthreads();
  u16* O = qT + (size_t)n * BSTRIDE + (size_t)s0 * 256 + mh * 128;
  #pragma unroll
  for (int it = 0; it < 8; ++it) {
    const int row = it * 16 + (t >> 4);
    *(s16x8*)(O + (size_t)row * 256 + (t & 15) * 8) = *(const s16x8*)&smem[row * 136 + (t & 15) * 8];
  }
}

// ---------------- reduce rowsum partials -> inverse ----------------
__global__ __launch_bounds__(256) void k_inv(const float* __restrict__ ps, float* __restrict__ ise)
{
  const int i = blockIdx.x * 256 + threadIdx.x;   // 2048
  float s = 0.f;
  for (int b = 0; b < 256; ++b) s += ps[(size_t)b * 2048 + i];
  ise[i] = 1.f / s;
}

// ---------------- ctx split-K partials + fused attention-map partials ----------------
__global__ __launch_bounds__(64) void k_ctx_part(
    const u16* __restrict__ ek, const u16* __restrict__ vb, const float* __restrict__ ise,
    float* __restrict__ cpart, float* __restrict__ mpart)
{
  const int blk = blockIdx.x;            // nh*64 + chunk
  const int chunk = blk & 63, nh = blk >> 6;
  const int h = nh & 7, n = nh >> 3;
  const int lane = threadIdx.x;
  const int l15 = lane & 15, l4 = lane >> 4;
  const u16* kb = ek + ((size_t)n * 256 + h * 32) * HW;
  const u16* vv = vb + ((size_t)n * 256 + h * 32) * HW;
  const float iv0 = ise[n * 256 + h * 32 + l15];
  const float iv1 = ise[n * 256 + h * 32 + 16 + l15];
  f32x4 acc[2][2] = {};
  float macc[8][8] = {};
  const int sbase = chunk * 256 + l4 * 8;
  #pragma unroll
  for (int ks = 0; ks < 8; ++ks) {
    const int sb = sbase + ks * 32;
    bf16x8 ef[2], vf[2];
    #pragma unroll
    for (int g = 0; g < 2; ++g) {
      ef[g] = *(const bf16x8*)(kb + (size_t)(g * 16 + l15) * HW + sb);
      vf[g] = *(const bf16x8*)(vv + (size_t)(g * 16 + l15) * HW + sb);
    }
    #pragma unroll
    for (int j = 0; j < 8; ++j)
      macc[ks][j] = fmaf(iv0, (float)ef[0][j], fmaf(iv1, (float)ef[1][j], macc[ks][j]));
    #pragma unroll
    for (int a = 0; a < 2; ++a)
      #pragma unroll
      for (int b = 0; b < 2; ++b)
        acc[a][b] = __builtin_amdgcn_mfma_f32_16x16x32_bf16(ef[a], vf[b], acc[a][b], 0, 0, 0);
  }
  float* op = cpart + (size_t)blk * 1024;
  #pragma unroll
  for (int a = 0; a < 2; ++a)
    #pragma unroll
    for (int b = 0; b < 2; ++b)
      #pragma unroll
      for (int r = 0; r < 4; ++r)
        op[(a * 16 + l4 * 4 + r) * 32 + b * 16 + l15] = acc[a][b][r];
  #pragma unroll
  for (int ks = 0; ks < 8; ++ks)
    #pragma unroll
    for (int j = 0; j < 8; ++j) {
      float v = macc[ks][j];
      v += __shfl_xor(v, 1); v += __shfl_xor(v, 2);
      v += __shfl_xor(v, 4); v += __shfl_xor(v, 8);
      macc[ks][j] = v;
    }
  if (l15 == 0) {
    float* mp = mpart + ((size_t)h * 8 + n) * HW + sbase;
    #pragma unroll
    for (int ks = 0; ks < 8; ++ks) {
      f32x4 a = {macc[ks][0], macc[ks][1], macc[ks][2], macc[ks][3]};
      f32x4 b = {macc[ks][4], macc[ks][5], macc[ks][6], macc[ks][7]};
      *(f32x4*)(mp + ks * 32)     = a;
      *(f32x4*)(mp + ks * 32 + 4) = b;
    }
  }
}

// ---------------- fused post: blocks 0..63 = ctx_reduce+mmat ; 64..191 = map_reduce ----------------
__global__ __launch_bounds__(256) void k_post(
    const float* __restrict__ cpart, const float* __restrict__ ise,
    const float* __restrict__ Wr, const float* __restrict__ mpart,
    u16* __restrict__ Mb, float* __restrict__ dctx, float* __restrict__ dmap)
{
  const int t = threadIdx.x;
  if (blockIdx.x < 64) {
    const int nh = blockIdx.x, n = nh >> 3, h = nh & 7;
    __shared__ float cl[1024];
    f32x4 a = {};
    for (int c = 0; c < 64; ++c) a += *(const f32x4*)(cpart + ((size_t)nh * 64 + c) * 1024 + t * 4);
    const float inv = ise[n * 256 + h * 32 + (t >> 3)];
    a *= inv;
    *(f32x4*)(cl + t * 4) = a;
    if (h == 7) *(f32x4*)(dctx + (size_t)n * 1024 + t * 4) = a;
    __syncthreads();
    const int o = t;
    float wr[32];
    const float* wp = Wr + (size_t)o * 256 + h * 32;
    #pragma unroll
    for (int v = 0; v < 32; ++v) wr[v] = wp[v];
    u16* mp = Mb + ((size_t)n * 256 + o) * 256 + h * 32;
    #pragma unroll 4
    for (int k = 0; k < 32; ++k) {
      float s = 0.f;
      #pragma unroll
      for (int v = 0; v < 32; ++v) s += wr[v] * cl[k * 32 + v];
      mp[k] = f2bf(s);
    }
  } else {
    const int i = (blockIdx.x - 64) * 256 + t;   // 32768 threads, f32x4 each
    f32x4 a = {};
    #pragma unroll
    for (int h = 0; h < 8; ++h) a += *(const f32x4*)(mpart + (size_t)h * 131072 + (size_t)i * 4);
    a *= (1.0f / 256.0f);
    *(f32x4*)(dmap + (size_t)i * 4) = a;
  }
}

// ---------------- final GEMM multi-tile (r9-verbatim): attn[o][s] = M·Q^T + br, f32 ----------------
__global__ __launch_bounds__(256, 2) void k_attn2(
    const u16* __restrict__ Mb, const u16* __restrict__ qT, const float* __restrict__ br,
    float* __restrict__ Out)
{
  __shared__ u16 smem[32768];
  const int t = threadIdx.x;
  const int L = blockIdx.x;
  const int n = L & 7;
  const int idx = L >> 3;
  const int mb = idx & 1;
  const int sq = idx >> 1;
  const int m0 = mb * 128;
  const int lane = t & 63;
  const int l15 = lane & 15, l4 = (lane >> 4) & 3;
  const int wv = t >> 6;
  const int wm = (wv & 1) * 64, wn = (wv >> 1) * 64;
  const u16* Ab = Mb + (size_t)n * 65536 + (size_t)m0 * 256;
  const u16* Bb = qT + (size_t)n * BSTRIDE;
  u16* Al = smem;
  u16* Bl = smem + 16384;

  float biasv[4];
  #pragma unroll
  for (int mf = 0; mf < 4; ++mf) biasv[mf] = br[m0 + wm + mf * 16 + l15];

  const int rr = t >> 3;
  const int csh = t & 7;
  auto STAGE = [&](int buf, int it) {
    const int k0 = (it & 3) * 64;
    const size_t s_t0 = (size_t)((sq * 4 + (it >> 2)) * 128);
    #pragma unroll
    for (int i = 0; i < 4; ++i) {
      const int row = i * 32 + rr;
      const int cs = (csh ^ (row & 7)) * 8;
      gld16(Ab + (size_t)row * 256 + k0 + cs,  Al + buf * 8192 + i * 2048 + t * 8);
      gld16(Bb + (s_t0 + row) * 256 + k0 + cs, Bl + buf * 8192 + i * 2048 + t * 8);
    }
  };

  f32x4 acc[4][4] = {};
  STAGE(0, 0); STAGE(1, 1);

  float* ob = Out + (size_t)n * BSTRIDE;

  #pragma unroll
  for (int it = 0; it < 16; ++it) {
    if (it == 15)                          asm volatile("s_waitcnt vmcnt(0)" ::: "memory");
    else if ((it & 3) <= 1 && it >= 4)     asm volatile("s_waitcnt vmcnt(24)" ::: "memory");
    else                                   asm volatile("s_waitcnt vmcnt(8)" ::: "memory");
    __builtin_amdgcn_s_barrier();

    const int buf = it & 1;
    #pragma unroll
    for (int ks = 0; ks < 2; ++ks) {
      bf16x8 af[4], bff[4];
      #pragma unroll
      for (int g = 0; g < 4; ++g) {
        const int mrow = wm + g * 16 + l15;
        const int srow = wn + g * 16 + l15;
        af[g]  = *(const bf16x8*)&Al[buf * 8192 + mrow * 64 + (((ks * 4 + l4) ^ (mrow & 7)) * 8)];
        bff[g] = *(const bf16x8*)&Bl[buf * 8192 + srow * 64 + (((ks * 4 + l4) ^ (srow & 7)) * 8)];
      }
      __builtin_amdgcn_s_setprio(1);
      #pragma unroll
      for (int sf = 0; sf < 4; ++sf)
        #pragma unroll
        for (int mf = 0; mf < 4; ++mf)
          acc[sf][mf] = __builtin_amdgcn_mfma_f32_16x16x32_bf16(bff[sf], af[mf], acc[sf][mf], 0, 0, 0);
      __builtin_amdgcn_s_setprio(0);
    }
    asm volatile("s_waitcnt lgkmcnt(0)" ::: "memory");
    __builtin_amdgcn_s_barrier();
    if (it < 14) STAGE(buf, it + 2);

    if ((it & 3) == 3) {
      const int s0t = (sq * 4 + (it >> 2)) * 128;
      #pragma unroll
      for (int sf = 0; sf < 4; ++sf)
        #pragma unroll
        for (int mf = 0; mf < 4; ++mf) {
          f32x4 o = acc[sf][mf] + biasv[mf];
          *(f32x4*)(ob + (size_t)(m0 + wm + mf * 16 + l15) * HW + s0t + wn + sf * 16 + l4 * 4) = o;
          acc[sf][mf] = f32x4{0.f, 0.f, 0.f, 0.f};
        }
    }
  }
}

extern "C" void kernel_launch(void* const* d_in, const int* in_sizes, int n_in,
                              void* d_out, int out_size, void* d_ws, size_t ws_size,
                              hipStream_t stream)
{
  (void)in_sizes; (void)n_in; (void)out_size; (void)ws_size;
  const float* x  = (const float*)d_in[0];
  const float* Wk = (const float*)d_in[1];
  const float* bk = (const float*)d_in[2];
  const float* Wq = (const float*)d_in[3];
  const float* bq = (const float*)d_in[4];
  const float* Wv = (const float*)d_in[5];
  const float* bv = (const float*)d_in[6];
  const float* Wr = (const float*)d_in[7];
  const float* br = (const float*)d_in[8];

  char* ws = (char*)d_ws;
  u16*   xbT  = (u16*)(ws + oXBT);
  u16*   ek   = (u16*)(ws + oEK);
  u16*   qT   = (u16*)(ws + oQT);
  u16*   vb   = (u16*)(ws + oVB);
  u16*   Wkqv = (u16*)(ws + oWK);
  float* bias = (float*)(ws + oBIAS);
  float* ise  = (float*)(ws + oISE);
  float* ps   = (float*)(ws + oPS);
  u16*   Mb   = (u16*)(ws + oMB);
  float* cpart= (float*)(ws + oCPART);
  float* mpart= (float*)(ws + oMPART);

  float* attn = (float*)d_out;                    // [8][256][HW]
  float* dctx = (float*)d_out + 33554432;         // [8][32][32]
  float* dmap = (float*)d_out + 33562624;         // [8][HW]

  k_pt<<<2112, 256, 0, stream>>>(x, Wk, Wq, Wv, bk, bq, bv, xbT, Wkqv, bias);
  k_proj3<<<2048, 256, 0, stream>>>(Wkqv, xbT, bias, ek, qT, vb, ps);
  k_inv<<<8, 256, 0, stream>>>(ps, ise);
  k_ctx_part<<<4096, 64, 0, stream>>>(ek, vb, ise, cpart, mpart);
  k_post<<<192, 256, 0, stream>>>(cpart, ise, Wr, mpart, Mb, dctx, dmap);
  k_attn2<<<512, 256, 0, stream>>>(Mb, qT, br, attn);
}

// Round 14
// 266.459 us; speedup vs baseline: 1.6596x; 1.0293x over previous
//
#include <hip/hip_runtime.h>
#include <hip/hip_bf16.h>

typedef float f32x4 __attribute__((ext_vector_type(4)));
typedef short s16x8 __attribute__((ext_vector_type(8)));
typedef short s16x4 __attribute__((ext_vector_type(4)));
typedef __bf16 bf16x8 __attribute__((ext_vector_type(8)));
typedef unsigned short u16;

#define DEVI __device__ __forceinline__

static constexpr int    HW      = 16384;
static constexpr size_t BSTRIDE = (size_t)256 * HW;

// ---- workspace byte offsets ----
static constexpr size_t oXBT   = 0;                                    // (unused now)
static constexpr size_t oEK    = oXBT  + (size_t)8 * HW * 256 * 2;     // bf16 [8][256][HW] exp(keys)
static constexpr size_t oQT    = oEK   + (size_t)8 * 256 * HW * 2;     // bf16 [8][HW][256] softmaxed Q, transposed
static constexpr size_t oVB    = oQT   + (size_t)8 * HW * 256 * 2;     // bf16 [8][256][HW]
static constexpr size_t oWK    = oVB   + (size_t)8 * 256 * HW * 2;     // bf16 [768][256]
static constexpr size_t oBIAS  = oWK   + (size_t)768 * 256 * 2;        // f32 [768]
static constexpr size_t oISE   = oBIAS + 4096;                         // f32 [8][256] inv row-sum-exp
static constexpr size_t oPS    = oISE  + 8192;                         // f32 [256][8][256] rowsum partials
static constexpr size_t oCTX   = oPS   + (size_t)256 * 2048 * 4;       // (unused)
static constexpr size_t oMB    = oCTX  + (size_t)64 * 1024 * 4;        // bf16 [8][256][256]
static constexpr size_t oCPART = oMB   + (size_t)8 * 256 * 256 * 2;    // f32 [4096][1024]
static constexpr size_t oMPART = oCPART + (size_t)4096 * 1024 * 4;     // f32 [8][8][HW]

DEVI float bf2f(short x) {
  unsigned u = ((unsigned)(unsigned short)x) << 16;
  return __builtin_bit_cast(float, u);
}
DEVI u16 f2bf(float x) { return __builtin_bit_cast(u16, (__bf16)x); }

DEVI void gld16(const void* g, void* l) {
  __builtin_amdgcn_global_load_lds(
      (__attribute__((address_space(1))) void*)(g),
      (__attribute__((address_space(3))) void*)(l), 16, 0, 0);
}

// ---------------- tiny prep: pack Wk|Wq|Wv -> bf16 [768][256], biases -> f32 [768] ----------------
__global__ __launch_bounds__(256) void k_prep(
    const float* __restrict__ Wk, const float* __restrict__ Wq, const float* __restrict__ Wv,
    const float* __restrict__ bk, const float* __restrict__ bq, const float* __restrict__ bv,
    u16* __restrict__ Wkqv, float* __restrict__ bias)
{
  int i = blockIdx.x * 256 + threadIdx.x;
  for (int p = i; p < 768 * 256; p += 64 * 256) {
    float v = (p < 65536) ? Wk[p] : (p < 131072 ? Wq[p - 65536] : Wv[p - 131072]);
    Wkqv[p] = f2bf(v);
  }
  if (i < 768) bias[i] = (i < 256) ? bk[i] : (i < 512 ? bq[i - 256] : bv[i - 512]);
}

// ================= fused transpose + B-resident 3-operator projection GEMM =================
// Block = (n, mh, sb): B-panel staged DIRECTLY FROM x (f32 [c][s] -> bf16 [s][c] swizzled LDS,
// 64KB, once); ops K (g0-7, swapped), V (g8-15, swapped), Q (g16-23, unswapped) stream 8KB
// A-tiles through a 16KB dbuf. Q epilogue reuses dead B region for the r7 overlay transpose.
// A-swizzle f(r) = (r&3)^((r>>2)&3) both-sides (2-way banked). B-swizzle c-chunk ^ (s&7).
__global__ __launch_bounds__(256, 2) void k_projX(
    const float* __restrict__ x,
    const u16* __restrict__ W, const float* __restrict__ bias,
    u16* __restrict__ ek, u16* __restrict__ qT, u16* __restrict__ vb, float* __restrict__ ps)
{
  __shared__ u16 smem[40960];          // B [0,32768) u16 ; A dbuf [32768,40960)
  const int t = threadIdx.x;
  const int L = blockIdx.x;
  const int n = L & 7;                 // batch == XCD
  const int idx = L >> 3;              // 0..255
  const int mh = idx & 1;              // mh pair adjacent -> x-panel L2 reuse
  const int sb = idx >> 1;             // 0..127
  const int m0 = mh * 128;
  const int s0 = sb * 128;
  const int lane = t & 63;
  const int l15 = lane & 15, l4 = (lane >> 4) & 3;
  const int wv = t >> 6;
  const int wm = (wv & 1) * 64, wn = (wv >> 1) * 64;

  float bK[4], bV[4];
  #pragma unroll
  for (int mf = 0; mf < 4; ++mf) {
    bK[mf] = bias[m0 + wm + mf * 16 + l15];
    bV[mf] = bias[512 + m0 + wm + mf * 16 + l15];
  }

  // ---- B prologue: x[c=t][s0..s0+127] f32 -> bf16 transposed into swizzled LDS ----
  {
    const float* xr = x + ((size_t)n * 256 + t) * HW + s0;
    const int ch = t >> 3, cw = t & 7;
    #pragma unroll
    for (int i = 0; i < 32; ++i) {
      f32x4 v = *(const f32x4*)(xr + i * 4);
      #pragma unroll
      for (int j = 0; j < 4; ++j) {
        const int s = i * 4 + j;
        smem[s * 256 + ((ch ^ (s & 7)) * 8) + cw] = f2bf(v[j]);
      }
    }
  }
  __syncthreads();                     // B visible to all; VMEM queue empty

  auto STAGEA = [&](int g) {
    const int kt = g & 7;
    const int op = g >> 3;
    const int wr0 = (op == 0) ? 0 : (op == 1 ? 512 : 256);
    const u16* Ab = W + (size_t)(wr0 + m0) * 256;
    #pragma unroll
    for (int i = 0; i < 2; ++i) {
      const int f = i * 256 + t;
      const int row = f >> 2, c = f & 3;
      const int fa = (row & 3) ^ ((row >> 2) & 3);
      gld16(Ab + (size_t)row * 256 + kt * 32 + ((c ^ fa) * 8),
            smem + 32768 + (g & 1) * 4096 + f * 8);
    }
  };

  STAGEA(0); STAGEA(1);

  f32x4 acc[4][4] = {};
  u16* ekb = ek + (size_t)n * BSTRIDE;
  u16* vbb = vb + (size_t)n * BSTRIDE;

  #pragma unroll
  for (int g = 0; g < 24; ++g) {
    // gate: A(g) resident; A(g+1) in flight. In-order VMEM retirement keeps vmcnt(2)
    // correct across older epilogue stores.
    if (g == 23) asm volatile("s_waitcnt vmcnt(0)" ::: "memory");
    else         asm volatile("s_waitcnt vmcnt(2)" ::: "memory");
    __builtin_amdgcn_s_barrier();

    const int kt = g & 7;
    bf16x8 af[4], bff[4];
    #pragma unroll
    for (int gg = 0; gg < 4; ++gg) {
      const int mrow = wm + gg * 16 + l15;
      const int srow = wn + gg * 16 + l15;
      const int cidx = kt * 4 + l4;
      const int fa = (mrow & 3) ^ ((mrow >> 2) & 3);
      af[gg]  = *(const bf16x8*)&smem[32768 + (g & 1) * 4096 + mrow * 32 + ((l4 ^ fa) * 8)];
      bff[gg] = *(const bf16x8*)&smem[srow * 256 + ((cidx ^ (srow & 7)) * 8)];
    }
    __builtin_amdgcn_s_setprio(1);
    if (g < 16) {
      #pragma unroll
      for (int sf = 0; sf < 4; ++sf)
        #pragma unroll
        for (int mf = 0; mf < 4; ++mf)
          acc[sf][mf] = __builtin_amdgcn_mfma_f32_16x16x32_bf16(bff[sf], af[mf], acc[sf][mf], 0, 0, 0);
    } else {
      #pragma unroll
      for (int mg = 0; mg < 4; ++mg)
        #pragma unroll
        for (int ng = 0; ng < 4; ++ng)
          acc[mg][ng] = __builtin_amdgcn_mfma_f32_16x16x32_bf16(af[mg], bff[ng], acc[mg][ng], 0, 0, 0);
    }
    __builtin_amdgcn_s_setprio(0);

    asm volatile("s_waitcnt lgkmcnt(0)" ::: "memory");   // frag reads of Abuf retired
    __builtin_amdgcn_s_barrier();
    if (g < 22) STAGEA(g + 2);

    if (g == 7) {
      // ---- keys epilogue (swapped layout) ----
      float rs[4] = {0.f, 0.f, 0.f, 0.f};
      #pragma unroll
      for (int sf = 0; sf < 4; ++sf)
        #pragma unroll
        for (int mf = 0; mf < 4; ++mf) {
          s16x4 pk;
          #pragma unroll
          for (int r = 0; r < 4; ++r) {
            const float e = __expf(acc[sf][mf][r] + bK[mf]);
            rs[mf] += e;
            pk[r] = (short)f2bf(e);
          }
          *(s16x4*)(ekb + (size_t)(m0 + wm + mf * 16 + l15) * HW + s0 + wn + sf * 16 + l4 * 4) = pk;
        }
      #pragma unroll
      for (int mf = 0; mf < 4; ++mf) {
        float v = rs[mf];
        v += __shfl_xor(v, 16); v += __shfl_xor(v, 32);
        if (l4 == 0)
          ps[((size_t)(sb * 2 + (wn >> 6))) * 2048 + n * 256 + m0 + wm + mf * 16 + l15] = v;
      }
      #pragma unroll
      for (int sf = 0; sf < 4; ++sf)
        #pragma unroll
        for (int mf = 0; mf < 4; ++mf) acc[sf][mf] = f32x4{0.f, 0.f, 0.f, 0.f};
    } else if (g == 15) {
      // ---- values epilogue ----
      #pragma unroll
      for (int sf = 0; sf < 4; ++sf)
        #pragma unroll
        for (int mf = 0; mf < 4; ++mf) {
          s16x4 pk;
          #pragma unroll
          for (int r = 0; r < 4; ++r) pk[r] = (short)f2bf(acc[sf][mf][r] + bV[mf]);
          *(s16x4*)(vbb + (size_t)(m0 + wm + mf * 16 + l15) * HW + s0 + wn + sf * 16 + l4 * 4) = pk;
        }
      #pragma unroll
      for (int sf = 0; sf < 4; ++sf)
        #pragma unroll
        for (int mf = 0; mf < 4; ++mf) acc[sf][mf] = f32x4{0.f, 0.f, 0.f, 0.f};
    }
  }

  // ---- Q epilogue (unswapped; r7 overlay transpose in dead B region) ----
  #pragma unroll
  for (int mg = 0; mg < 4; ++mg)
    #pragma unroll
    for (int r = 0; r < 4; ++r) {
      const float bb = bias[256 + m0 + wm + mg * 16 + l4 * 4 + r];
      #pragma unroll
      for (int ng = 0; ng < 4; ++ng) acc[mg][ng][r] += bb;
    }
  #pragma unroll
  for (int hh = 0; hh < 2; ++hh)
    #pragma unroll
    for (int ng = 0; ng < 4; ++ng) {
      float s = 0.f;
      #pragma unroll
      for (int mg = hh * 2; mg < hh * 2 + 2; ++mg)
        #pragma unroll
        for (int r = 0; r < 4; ++r) { const float e = __expf(acc[mg][ng][r]); acc[mg][ng][r] = e; s += e; }
      s += __shfl_xor(s, 16);
      s += __shfl_xor(s, 32);
      const float inv = 1.f / s;
      #pragma unroll
      for (int mg = hh * 2; mg < hh * 2 + 2; ++mg)
        #pragma unroll
        for (int r = 0; r < 4; ++r) acc[mg][ng][r] *= inv;
    }
  __syncthreads();
  #pragma unroll
  for (int mg = 0; mg < 4; ++mg)
    #pragma unroll
    for (int ng = 0; ng < 4; ++ng)
      #pragma unroll
      for (int r = 0; r < 4; ++r) {
        const int srow = wn + ng * 16 + l15;
        const int mcol = wm + mg * 16 + l4 * 4 + r;
        smem[srow * 136 + mcol] = f2bf(acc[mg][ng][r]);
      }
  __syncthreads();
  u16* O = qT + (size_t)n * BSTRIDE + (size_t)s0 * 256 + mh * 128;
  #pragma unroll
  for (int it = 0; it < 8; ++it) {
    const int row = it * 16 + (t >> 4);
    *(s16x8*)(O + (size_t)row * 256 + (t & 15) * 8) = *(const s16x8*)&smem[row * 136 + (t & 15) * 8];
  }
}

// ---------------- reduce rowsum partials -> inverse ----------------
__global__ __launch_bounds__(256) void k_inv(const float* __restrict__ ps, float* __restrict__ ise)
{
  const int i = blockIdx.x * 256 + threadIdx.x;   // 2048
  float s = 0.f;
  for (int b = 0; b < 256; ++b) s += ps[(size_t)b * 2048 + i];
  ise[i] = 1.f / s;
}

// ---------------- ctx split-K partials + fused attention-map partials ----------------
__global__ __launch_bounds__(64) void k_ctx_part(
    const u16* __restrict__ ek, const u16* __restrict__ vb, const float* __restrict__ ise,
    float* __restrict__ cpart, float* __restrict__ mpart)
{
  const int blk = blockIdx.x;            // nh*64 + chunk
  const int chunk = blk & 63, nh = blk >> 6;
  const int h = nh & 7, n = nh >> 3;
  const int lane = threadIdx.x;
  const int l15 = lane & 15, l4 = lane >> 4;
  const u16* kb = ek + ((size_t)n * 256 + h * 32) * HW;
  const u16* vv = vb + ((size_t)n * 256 + h * 32) * HW;
  const float iv0 = ise[n * 256 + h * 32 + l15];
  const float iv1 = ise[n * 256 + h * 32 + 16 + l15];
  f32x4 acc[2][2] = {};
  float macc[8][8] = {};
  const int sbase = chunk * 256 + l4 * 8;
  #pragma unroll
  for (int ks = 0; ks < 8; ++ks) {
    const int sb = sbase + ks * 32;
    bf16x8 ef[2], vf[2];
    #pragma unroll
    for (int g = 0; g < 2; ++g) {
      ef[g] = *(const bf16x8*)(kb + (size_t)(g * 16 + l15) * HW + sb);
      vf[g] = *(const bf16x8*)(vv + (size_t)(g * 16 + l15) * HW + sb);
    }
    #pragma unroll
    for (int j = 0; j < 8; ++j)
      macc[ks][j] = fmaf(iv0, (float)ef[0][j], fmaf(iv1, (float)ef[1][j], macc[ks][j]));
    #pragma unroll
    for (int a = 0; a < 2; ++a)
      #pragma unroll
      for (int b = 0; b < 2; ++b)
        acc[a][b] = __builtin_amdgcn_mfma_f32_16x16x32_bf16(ef[a], vf[b], acc[a][b], 0, 0, 0);
  }
  float* op = cpart + (size_t)blk * 1024;
  #pragma unroll
  for (int a = 0; a < 2; ++a)
    #pragma unroll
    for (int b = 0; b < 2; ++b)
      #pragma unroll
      for (int r = 0; r < 4; ++r)
        op[(a * 16 + l4 * 4 + r) * 32 + b * 16 + l15] = acc[a][b][r];
  #pragma unroll
  for (int ks = 0; ks < 8; ++ks)
    #pragma unroll
    for (int j = 0; j < 8; ++j) {
      float v = macc[ks][j];
      v += __shfl_xor(v, 1); v += __shfl_xor(v, 2);
      v += __shfl_xor(v, 4); v += __shfl_xor(v, 8);
      macc[ks][j] = v;
    }
  if (l15 == 0) {
    float* mp = mpart + ((size_t)h * 8 + n) * HW + sbase;
    #pragma unroll
    for (int ks = 0; ks < 8; ++ks) {
      f32x4 a = {macc[ks][0], macc[ks][1], macc[ks][2], macc[ks][3]};
      f32x4 b = {macc[ks][4], macc[ks][5], macc[ks][6], macc[ks][7]};
      *(f32x4*)(mp + ks * 32)     = a;
      *(f32x4*)(mp + ks * 32 + 4) = b;
    }
  }
}

// ---------------- fused post: blocks 0..63 = ctx_reduce+mmat ; 64..191 = map_reduce ----------------
__global__ __launch_bounds__(256) void k_post(
    const float* __restrict__ cpart, const float* __restrict__ ise,
    const float* __restrict__ Wr, const float* __restrict__ mpart,
    u16* __restrict__ Mb, float* __restrict__ dctx, float* __restrict__ dmap)
{
  const int t = threadIdx.x;
  if (blockIdx.x < 64) {
    const int nh = blockIdx.x, n = nh >> 3, h = nh & 7;
    __shared__ float cl[1024];
    f32x4 a = {};
    for (int c = 0; c < 64; ++c) a += *(const f32x4*)(cpart + ((size_t)nh * 64 + c) * 1024 + t * 4);
    const float inv = ise[n * 256 + h * 32 + (t >> 3)];
    a *= inv;
    *(f32x4*)(cl + t * 4) = a;
    if (h == 7) *(f32x4*)(dctx + (size_t)n * 1024 + t * 4) = a;
    __syncthreads();
    const int o = t;
    float wr[32];
    const float* wp = Wr + (size_t)o * 256 + h * 32;
    #pragma unroll
    for (int v = 0; v < 32; ++v) wr[v] = wp[v];
    u16* mp = Mb + ((size_t)n * 256 + o) * 256 + h * 32;
    #pragma unroll 4
    for (int k = 0; k < 32; ++k) {
      float s = 0.f;
      #pragma unroll
      for (int v = 0; v < 32; ++v) s += wr[v] * cl[k * 32 + v];
      mp[k] = f2bf(s);
    }
  } else {
    const int i = (blockIdx.x - 64) * 256 + t;   // 32768 threads, f32x4 each
    f32x4 a = {};
    #pragma unroll
    for (int h = 0; h < 8; ++h) a += *(const f32x4*)(mpart + (size_t)h * 131072 + (size_t)i * 4);
    a *= (1.0f / 256.0f);
    *(f32x4*)(dmap + (size_t)i * 4) = a;
  }
}

// ---------------- final GEMM multi-tile (r9-verbatim): attn[o][s] = M·Q^T + br, f32 ----------------
__global__ __launch_bounds__(256, 2) void k_attn2(
    const u16* __restrict__ Mb, const u16* __restrict__ qT, const float* __restrict__ br,
    float* __restrict__ Out)
{
  __shared__ u16 smem[32768];
  const int t = threadIdx.x;
  const int L = blockIdx.x;
  const int n = L & 7;
  const int idx = L >> 3;
  const int mb = idx & 1;
  const int sq = idx >> 1;
  const int m0 = mb * 128;
  const int lane = t & 63;
  const int l15 = lane & 15, l4 = (lane >> 4) & 3;
  const int wv = t >> 6;
  const int wm = (wv & 1) * 64, wn = (wv >> 1) * 64;
  const u16* Ab = Mb + (size_t)n * 65536 + (size_t)m0 * 256;
  const u16* Bb = qT + (size_t)n * BSTRIDE;
  u16* Al = smem;
  u16* Bl = smem + 16384;

  float biasv[4];
  #pragma unroll
  for (int mf = 0; mf < 4; ++mf) biasv[mf] = br[m0 + wm + mf * 16 + l15];

  const int rr = t >> 3;
  const int csh = t & 7;
  auto STAGE = [&](int buf, int it) {
    const int k0 = (it & 3) * 64;
    const size_t s_t0 = (size_t)((sq * 4 + (it >> 2)) * 128);
    #pragma unroll
    for (int i = 0; i < 4; ++i) {
      const int row = i * 32 + rr;
      const int cs = (csh ^ (row & 7)) * 8;
      gld16(Ab + (size_t)row * 256 + k0 + cs,  Al + buf * 8192 + i * 2048 + t * 8);
      gld16(Bb + (s_t0 + row) * 256 + k0 + cs, Bl + buf * 8192 + i * 2048 + t * 8);
    }
  };

  f32x4 acc[4][4] = {};
  STAGE(0, 0); STAGE(1, 1);

  float* ob = Out + (size_t)n * BSTRIDE;

  #pragma unroll
  for (int it = 0; it < 16; ++it) {
    if (it == 15)                          asm volatile("s_waitcnt vmcnt(0)" ::: "memory");
    else if ((it & 3) <= 1 && it >= 4)     asm volatile("s_waitcnt vmcnt(24)" ::: "memory");
    else                                   asm volatile("s_waitcnt vmcnt(8)" ::: "memory");
    __builtin_amdgcn_s_barrier();

    const int buf = it & 1;
    #pragma unroll
    for (int ks = 0; ks < 2; ++ks) {
      bf16x8 af[4], bff[4];
      #pragma unroll
      for (int g = 0; g < 4; ++g) {
        const int mrow = wm + g * 16 + l15;
        const int srow = wn + g * 16 + l15;
        af[g]  = *(const bf16x8*)&Al[buf * 8192 + mrow * 64 + (((ks * 4 + l4) ^ (mrow & 7)) * 8)];
        bff[g] = *(const bf16x8*)&Bl[buf * 8192 + srow * 64 + (((ks * 4 + l4) ^ (srow & 7)) * 8)];
      }
      __builtin_amdgcn_s_setprio(1);
      #pragma unroll
      for (int sf = 0; sf < 4; ++sf)
        #pragma unroll
        for (int mf = 0; mf < 4; ++mf)
          acc[sf][mf] = __builtin_amdgcn_mfma_f32_16x16x32_bf16(bff[sf], af[mf], acc[sf][mf], 0, 0, 0);
      __builtin_amdgcn_s_setprio(0);
    }
    asm volatile("s_waitcnt lgkmcnt(0)" ::: "memory");
    __builtin_amdgcn_s_barrier();
    if (it < 14) STAGE(buf, it + 2);

    if ((it & 3) == 3) {
      const int s0t = (sq * 4 + (it >> 2)) * 128;
      #pragma unroll
      for (int sf = 0; sf < 4; ++sf)
        #pragma unroll
        for (int mf = 0; mf < 4; ++mf) {
          f32x4 o = acc[sf][mf] + biasv[mf];
          *(f32x4*)(ob + (size_t)(m0 + wm + mf * 16 + l15) * HW + s0t + wn + sf * 16 + l4 * 4) = o;
          acc[sf][mf] = f32x4{0.f, 0.f, 0.f, 0.f};
        }
    }
  }
}

extern "C" void kernel_launch(void* const* d_in, const int* in_sizes, int n_in,
                              void* d_out, int out_size, void* d_ws, size_t ws_size,
                              hipStream_t stream)
{
  (void)in_sizes; (void)n_in; (void)out_size; (void)ws_size;
  const float* x  = (const float*)d_in[0];
  const float* Wk = (const float*)d_in[1];
  const float* bk = (const float*)d_in[2];
  const float* Wq = (const float*)d_in[3];
  const float* bq = (const float*)d_in[4];
  const float* Wv = (const float*)d_in[5];
  const float* bv = (const float*)d_in[6];
  const float* Wr = (const float*)d_in[7];
  const float* br = (const float*)d_in[8];

  char* ws = (char*)d_ws;
  u16*   ek   = (u16*)(ws + oEK);
  u16*   qT   = (u16*)(ws + oQT);
  u16*   vb   = (u16*)(ws + oVB);
  u16*   Wkqv = (u16*)(ws + oWK);
  float* bias = (float*)(ws + oBIAS);
  float* ise  = (float*)(ws + oISE);
  float* ps   = (float*)(ws + oPS);
  u16*   Mb   = (u16*)(ws + oMB);
  float* cpart= (float*)(ws + oCPART);
  float* mpart= (float*)(ws + oMPART);

  float* attn = (float*)d_out;                    // [8][256][HW]
  float* dctx = (float*)d_out + 33554432;         // [8][32][32]
  float* dmap = (float*)d_out + 33562624;         // [8][HW]

  k_prep<<<64, 256, 0, stream>>>(Wk, Wq, Wv, bk, bq, bv, Wkqv, bias);
  k_projX<<<2048, 256, 0, stream>>>(x, Wkqv, bias, ek, qT, vb, ps);
  k_inv<<<8, 256, 0, stream>>>(ps, ise);
  k_ctx_part<<<4096, 64, 0, stream>>>(ek, vb, ise, cpart, mpart);
  k_post<<<192, 256, 0, stream>>>(cpart, ise, Wr, mpart, Mb, dctx, dmap);
  k_attn2<<<512, 256, 0, stream>>>(Mb, qT, br, attn);
}